// Round 1
// baseline (515.376 us; speedup 1.0000x reference)
//
#include <hip/hip_runtime.h>

#define Bsz 64
#define Tsz 2048
#define Esz 512
#define Asz 128
#define Rsz 1024
#define KP  576      // 512 (E) + 62 conv taps + 2 zero pad
#define TILE_M 64

typedef __bf16 bf16;
typedef __bf16 bf16x8 __attribute__((ext_vector_type(8)));
typedef __bf16 bf16x4 __attribute__((ext_vector_type(4)));
typedef float  f32x4  __attribute__((ext_vector_type(4)));

// ---------------- prep: Wext = [W_memory ; U]^T in bf16, pq = ah @ Wq ----------------
__global__ __launch_bounds__(128) void prep_kernel(
    const float* __restrict__ Wmem, const float* __restrict__ convw,
    const float* __restrict__ Wloc, const float* __restrict__ ah,
    const float* __restrict__ Wq, bf16* __restrict__ Wext,
    float* __restrict__ pq)
{
  int blk = blockIdx.x, tid = threadIdx.x;
  if (blk < Asz) {
    int a = blk;
    for (int e = tid; e < Esz; e += 128)
      Wext[a*KP + e] = (bf16)Wmem[e*Asz + a];
    if (tid < 64) {
      int j = tid;
      float u = 0.f;
      if (j < 62) {
        int c  = (j < 31) ? 0 : 1;
        int kk = (j < 31) ? j : j - 31;
        #pragma unroll
        for (int f = 0; f < 32; ++f)
          u += convw[f*62 + c*31 + kk] * Wloc[f*Asz + a];
      }
      Wext[a*KP + Esz + j] = (bf16)u;
    }
  } else {
    int b = blk - Asz;       // 64 blocks
    int a = tid;             // 128 threads
    float s = 0.f;
    for (int r = 0; r < Rsz; ++r)
      s += ah[b*Rsz + r] * Wq[r*Asz + a];
    pq[b*Asz + a] = s;
  }
}

// ---------------- main fused kernel ----------------
__global__ __launch_bounds__(256) void attn_main(
    const float* __restrict__ memory, const float* __restrict__ awcat,
    const int* __restrict__ mask, const bf16* __restrict__ Wext,
    const float* __restrict__ pq, const float* __restrict__ vw,
    const float* __restrict__ vb, float* __restrict__ out,
    float* __restrict__ ws_align)
{
  __shared__ bf16  Afull[TILE_M * KP];   // 73728 B, XOR-chunk swizzled
  __shared__ float s_pq[Asz];
  __shared__ float s_vw[Asz];
  __shared__ float s_ebuf[TILE_M];
  __shared__ float s_align[TILE_M];

  int tid = threadIdx.x;
  int b  = blockIdx.x >> 5;
  int t0 = (blockIdx.x & 31) << 6;

  // stage memory tile fp32 -> bf16 LDS (coalesced float4 loads)
  const float4* memv = (const float4*)(memory + (size_t)(b*Tsz + t0)*Esz);
  for (int i = tid; i < TILE_M*(Esz/4); i += 256) {
    int r = i >> 7, c4 = i & 127;
    float4 v = memv[r*128 + c4];
    int k = c4 * 4;
    int sw = (k >> 3) ^ (r & 7);
    int base = r*KP + sw*8 + (k & 7);
    bf16x4 p; p[0]=(bf16)v.x; p[1]=(bf16)v.y; p[2]=(bf16)v.z; p[3]=(bf16)v.w;
    *(bf16x4*)&Afull[base] = p;
  }
  // stage im2col'd aw window into K columns 512..575
  const float* aw = awcat + (size_t)b*2*Tsz;
  for (int i = tid; i < TILE_M*64; i += 256) {
    int r = i >> 6, j = i & 63;
    float val = 0.f;
    if (j < 62) {
      int c  = (j < 31) ? 0 : 1;
      int kk = (j < 31) ? j : j - 31;
      int t  = t0 + r + kk - 15;
      if (t >= 0 && t < Tsz) val = aw[c*Tsz + t];
    }
    int k = Esz + j;
    int sw = (k >> 3) ^ (r & 7);
    Afull[r*KP + sw*8 + (k & 7)] = (bf16)val;
  }
  if (tid < Asz) { s_pq[tid] = pq[b*Asz + tid]; s_vw[tid] = vw[tid]; }
  if (tid < TILE_M) s_ebuf[tid] = 0.f;
  __syncthreads();

  int w = tid >> 6, l = tid & 63;
  int quad = l >> 4, lrow = l & 15;

  f32x4 acc[4][2];
  #pragma unroll
  for (int mt = 0; mt < 4; ++mt)
    #pragma unroll
    for (int nt = 0; nt < 2; ++nt)
      acc[mt][nt] = (f32x4){0.f, 0.f, 0.f, 0.f};

  // K loop: 18 chunks of 32 (512 memory + 64 location)
  for (int kc = 0; kc < KP/32; ++kc) {
    int kbase = kc*32 + quad*8;
    bf16x8 bfrag[2];
    #pragma unroll
    for (int nt = 0; nt < 2; ++nt) {
      int acol = lrow + 16*(2*w + nt);
      bfrag[nt] = *(const bf16x8*)&Wext[acol*KP + kbase];   // L2-hot global
    }
    bf16x8 afrag[4];
    #pragma unroll
    for (int mt = 0; mt < 4; ++mt) {
      int r = mt*16 + lrow;
      int sw = ((kbase >> 3) ^ (r & 7));
      afrag[mt] = *(const bf16x8*)&Afull[r*KP + sw*8];
    }
    #pragma unroll
    for (int mt = 0; mt < 4; ++mt)
      #pragma unroll
      for (int nt = 0; nt < 2; ++nt)
        acc[mt][nt] = __builtin_amdgcn_mfma_f32_16x16x32_bf16(
            afrag[mt], bfrag[nt], acc[mt][nt], 0, 0, 0);
  }

  // energies: e_r = sum_a tanh(pm+pl+pq)*v_w   (C layout: col=lane&15, row=quad*4+reg)
  float partial[4][4];
  #pragma unroll
  for (int mt = 0; mt < 4; ++mt)
    #pragma unroll
    for (int rg = 0; rg < 4; ++rg) partial[mt][rg] = 0.f;
  #pragma unroll
  for (int nt = 0; nt < 2; ++nt) {
    int col = 16*(2*w + nt) + lrow;
    float vwc = s_vw[col], pqc = s_pq[col];
    #pragma unroll
    for (int mt = 0; mt < 4; ++mt)
      #pragma unroll
      for (int rg = 0; rg < 4; ++rg)
        partial[mt][rg] += tanhf(acc[mt][nt][rg] + pqc) * vwc;
  }
  #pragma unroll
  for (int off = 1; off < 16; off <<= 1)
    #pragma unroll
    for (int mt = 0; mt < 4; ++mt)
      #pragma unroll
      for (int rg = 0; rg < 4; ++rg)
        partial[mt][rg] += __shfl_xor(partial[mt][rg], off, 64);
  if (lrow == 0) {
    #pragma unroll
    for (int mt = 0; mt < 4; ++mt)
      #pragma unroll
      for (int rg = 0; rg < 4; ++rg)
        atomicAdd(&s_ebuf[mt*16 + quad*4 + rg], partial[mt][rg]);
  }
  __syncthreads();

  if (tid < TILE_M) {
    int t = t0 + tid;
    float al = s_ebuf[tid] + vb[0] + (float)mask[b*Tsz + t] * -1e25f;
    s_align[tid] = al;
    ws_align[b*Tsz + t] = al;
  }
  __syncthreads();

  // attention_output partial: out[b,e] += sum_r align[r] * mem[r,e]  (reuse LDS tile)
  float a0 = 0.f, a1 = 0.f;
  int k0 = tid, k1 = tid + 256;
  for (int r = 0; r < TILE_M; ++r) {
    float al = s_align[r];
    float m0 = (float)Afull[r*KP + (((k0 >> 3) ^ (r & 7)) << 3) + (k0 & 7)];
    float m1 = (float)Afull[r*KP + (((k1 >> 3) ^ (r & 7)) << 3) + (k1 & 7)];
    a0 += al * m0;
    a1 += al * m1;
  }
  atomicAdd(&out[b*Esz + k0], a0);
  atomicAdd(&out[b*Esz + k1], a1);
}

// ---------------- softmax over T per batch row ----------------
__global__ __launch_bounds__(256) void softmax_kernel(
    const float* __restrict__ ws_align, float* __restrict__ out_w)
{
  int b = blockIdx.x, tid = threadIdx.x;
  const float* row = ws_align + (size_t)b*Tsz;
  float vals[8];
  float lmax = -3.4e38f;
  #pragma unroll
  for (int i = 0; i < 8; ++i) { vals[i] = row[tid + i*256]; lmax = fmaxf(lmax, vals[i]); }
  #pragma unroll
  for (int off = 1; off < 64; off <<= 1) lmax = fmaxf(lmax, __shfl_xor(lmax, off, 64));
  __shared__ float smax[4], ssum[4];
  if ((tid & 63) == 0) smax[tid >> 6] = lmax;
  __syncthreads();
  float bmax = fmaxf(fmaxf(smax[0], smax[1]), fmaxf(smax[2], smax[3]));
  float lsum = 0.f;
  #pragma unroll
  for (int i = 0; i < 8; ++i) { vals[i] = __expf(vals[i] - bmax); lsum += vals[i]; }
  #pragma unroll
  for (int off = 1; off < 64; off <<= 1) lsum += __shfl_xor(lsum, off, 64);
  if ((tid & 63) == 0) ssum[tid >> 6] = lsum;
  __syncthreads();
  float inv = 1.f / (ssum[0] + ssum[1] + ssum[2] + ssum[3]);
  #pragma unroll
  for (int i = 0; i < 8; ++i) out_w[(size_t)b*Tsz + tid + i*256] = vals[i] * inv;
}

extern "C" void kernel_launch(void* const* d_in, const int* in_sizes, int n_in,
                              void* d_out, int out_size, void* d_ws, size_t ws_size,
                              hipStream_t stream) {
  const float* ah   = (const float*)d_in[0];
  const float* mem  = (const float*)d_in[1];
  const float* awc  = (const float*)d_in[2];
  const int*   mask = (const int*)d_in[3];
  const float* Wq   = (const float*)d_in[4];
  const float* Wm   = (const float*)d_in[5];
  const float* cw   = (const float*)d_in[6];
  const float* Wl   = (const float*)d_in[7];
  const float* vw   = (const float*)d_in[8];
  const float* vb   = (const float*)d_in[9];
  float* out = (float*)d_out;

  // ws layout: Wext bf16 [128][576] (147456 B) | pq f32 [64][128] (32768 B) | align f32 [64][2048]
  bf16*  Wext = (bf16*)d_ws;
  float* pq   = (float*)((char*)d_ws + 147456);
  float* wsa  = (float*)((char*)d_ws + 180224);

  hipMemsetAsync(out, 0, Bsz*Esz*sizeof(float), stream);  // attention_output accumulators
  prep_kernel<<<dim3(Asz + Bsz), 128, 0, stream>>>(Wm, cw, Wl, ah, Wq, Wext, pq);
  attn_main<<<dim3(Bsz*(Tsz/TILE_M)), 256, 0, stream>>>(mem, awc, mask, Wext, pq, vw, vb, out, wsa);
  softmax_kernel<<<dim3(Bsz), 256, 0, stream>>>(wsa, out + Bsz*Esz);
}

// Round 2
// 496.596 us; speedup vs baseline: 1.0378x; 1.0378x over previous
//
#include <hip/hip_runtime.h>

#define Bsz 64
#define Tsz 2048
#define Esz 512
#define Asz 128
#define Rsz 1024
#define KP  576      // 512 (E) + 62 conv taps + 2 zero pad
#define TILE_M 32

typedef __bf16 bf16;
typedef __bf16 bf16x8 __attribute__((ext_vector_type(8)));
typedef __bf16 bf16x4 __attribute__((ext_vector_type(4)));
typedef __bf16 bf16x2 __attribute__((ext_vector_type(2)));
typedef float  f32x4  __attribute__((ext_vector_type(4)));

// ---------------- prep: Wext = [W_memory ; U]^T bf16, pq = ah @ Wq ----------------
// grid = 224 blocks x 256 threads:
//   blocks 0..127   : Wext memory-part transpose (block = column a)
//   blocks 128..159 : Wext location-part U = conv_w^T @ W_loc
//   blocks 160..223 : pq (block = batch row b), 32 colgroups x 8 kgroups
__global__ __launch_bounds__(256) void prep_kernel(
    const float* __restrict__ Wmem, const float* __restrict__ convw,
    const float* __restrict__ Wloc, const float* __restrict__ ah,
    const float* __restrict__ Wq, bf16* __restrict__ Wext,
    float* __restrict__ pq)
{
  __shared__ f32x4 red[256];
  int blk = blockIdx.x, tid = threadIdx.x;
  if (blk < 128) {
    int a = blk;
    #pragma unroll
    for (int e = tid; e < Esz; e += 256)
      Wext[a*KP + e] = (bf16)Wmem[e*Asz + a];
  } else if (blk < 160) {
    int idx = (blk - 128)*256 + tid;      // 8192 = 128 a x 64 j
    int a = idx >> 6, j = idx & 63;
    float u = 0.f;
    if (j < 62) {
      int c  = (j < 31) ? 0 : 1;
      int kk = (j < 31) ? j : j - 31;
      #pragma unroll
      for (int f = 0; f < 32; ++f)
        u += convw[f*62 + c*31 + kk] * Wloc[f*Asz + a];
    }
    Wext[a*KP + Esz + j] = (bf16)u;
  } else {
    int b  = blk - 160;
    int cg = tid & 31;                    // 4 columns each
    int kg = tid >> 5;                    // 8 k-groups x 128 rows
    const float* ahb = ah + (size_t)b*Rsz;
    f32x4 s = (f32x4){0.f,0.f,0.f,0.f};
    int r0 = kg*128;
    for (int r = r0; r < r0 + 128; ++r) {
      float av = ahb[r];
      f32x4 wq = *(const f32x4*)&Wq[r*Asz + cg*4];
      s += av * wq;
    }
    red[tid] = s;
    __syncthreads();
    if (tid < 32) {
      f32x4 tot = red[tid];
      #pragma unroll
      for (int g = 1; g < 8; ++g) tot += red[g*32 + tid];
      *(f32x4*)&pq[b*Asz + tid*4] = tot;
    }
  }
}

// ---------------- main fused kernel ----------------
__global__ __launch_bounds__(256) void attn_main(
    const float* __restrict__ memory, const float* __restrict__ awcat,
    const int* __restrict__ mask, const bf16* __restrict__ Wext,
    const float* __restrict__ pq, const float* __restrict__ vw,
    const float* __restrict__ vb, float* __restrict__ out,
    float* __restrict__ ws_align)
{
  __shared__ bf16  Afull[TILE_M * KP];   // 36864 B, XOR-chunk swizzled
  __shared__ float s_pq[Asz];
  __shared__ float s_vw[Asz];
  __shared__ float s_ebuf[TILE_M];
  __shared__ float s_align[TILE_M];

  int tid = threadIdx.x;
  int b  = blockIdx.x >> 6;
  int t0 = (blockIdx.x & 63) << 5;

  // stage memory tile fp32 -> bf16 LDS (coalesced float4 loads)
  const float4* memv = (const float4*)(memory + (size_t)(b*Tsz + t0)*Esz);
  #pragma unroll
  for (int i = tid; i < TILE_M*(Esz/4); i += 256) {
    int r = i >> 7, c4 = i & 127;
    float4 v = memv[r*128 + c4];
    int k = c4 * 4;
    int sw = (k >> 3) ^ (r & 7);
    int base = r*KP + sw*8 + (k & 7);
    bf16x4 p; p[0]=(bf16)v.x; p[1]=(bf16)v.y; p[2]=(bf16)v.z; p[3]=(bf16)v.w;
    *(bf16x4*)&Afull[base] = p;
  }
  // stage im2col'd aw window into K columns 512..575
  const float* aw = awcat + (size_t)b*2*Tsz;
  #pragma unroll
  for (int i = tid; i < TILE_M*64; i += 256) {
    int r = i >> 6, j = i & 63;
    float val = 0.f;
    if (j < 62) {
      int c  = (j < 31) ? 0 : 1;
      int kk = (j < 31) ? j : j - 31;
      int t  = t0 + r + kk - 15;
      if (t >= 0 && t < Tsz) val = aw[c*Tsz + t];
    }
    int k = Esz + j;
    int sw = (k >> 3) ^ (r & 7);
    Afull[r*KP + sw*8 + (k & 7)] = (bf16)val;
  }
  if (tid < Asz) { s_pq[tid] = pq[b*Asz + tid]; s_vw[tid] = vw[tid]; }
  if (tid < TILE_M) s_ebuf[tid] = 0.f;
  __syncthreads();

  int w = tid >> 6, l = tid & 63;
  int quad = l >> 4, lrow = l & 15;

  f32x4 acc[2][2];
  #pragma unroll
  for (int mt = 0; mt < 2; ++mt)
    #pragma unroll
    for (int nt = 0; nt < 2; ++nt)
      acc[mt][nt] = (f32x4){0.f, 0.f, 0.f, 0.f};

  // K loop: 18 chunks of 32 (512 memory + 64 location)
  for (int kc = 0; kc < KP/32; ++kc) {
    int kbase = kc*32 + quad*8;
    bf16x8 bfrag[2];
    #pragma unroll
    for (int nt = 0; nt < 2; ++nt) {
      int acol = lrow + 16*(2*w + nt);
      bfrag[nt] = *(const bf16x8*)&Wext[acol*KP + kbase];   // L2-hot global
    }
    bf16x8 afrag[2];
    #pragma unroll
    for (int mt = 0; mt < 2; ++mt) {
      int r = mt*16 + lrow;
      int sw = ((kbase >> 3) ^ (r & 7));
      afrag[mt] = *(const bf16x8*)&Afull[r*KP + sw*8];
    }
    #pragma unroll
    for (int mt = 0; mt < 2; ++mt)
      #pragma unroll
      for (int nt = 0; nt < 2; ++nt)
        acc[mt][nt] = __builtin_amdgcn_mfma_f32_16x16x32_bf16(
            afrag[mt], bfrag[nt], acc[mt][nt], 0, 0, 0);
  }

  // energies: e_r = sum_a tanh(pm+pl+pq)*v_w   (C layout: col=lane&15, row=quad*4+reg)
  float partial[2][4];
  #pragma unroll
  for (int mt = 0; mt < 2; ++mt)
    #pragma unroll
    for (int rg = 0; rg < 4; ++rg) partial[mt][rg] = 0.f;
  #pragma unroll
  for (int nt = 0; nt < 2; ++nt) {
    int col = 16*(2*w + nt) + lrow;
    float vwc = s_vw[col], pqc = s_pq[col];
    #pragma unroll
    for (int mt = 0; mt < 2; ++mt)
      #pragma unroll
      for (int rg = 0; rg < 4; ++rg)
        partial[mt][rg] += tanhf(acc[mt][nt][rg] + pqc) * vwc;
  }
  #pragma unroll
  for (int off = 1; off < 16; off <<= 1)
    #pragma unroll
    for (int mt = 0; mt < 2; ++mt)
      #pragma unroll
      for (int rg = 0; rg < 4; ++rg)
        partial[mt][rg] += __shfl_xor(partial[mt][rg], off, 64);
  if (lrow == 0) {
    #pragma unroll
    for (int mt = 0; mt < 2; ++mt)
      #pragma unroll
      for (int rg = 0; rg < 4; ++rg)
        atomicAdd(&s_ebuf[mt*16 + quad*4 + rg], partial[mt][rg]);
  }
  __syncthreads();

  if (tid < TILE_M) {
    int t = t0 + tid;
    float al = s_ebuf[tid] + vb[0] + (float)mask[b*Tsz + t] * -1e25f;
    s_align[tid] = al;
    ws_align[b*Tsz + t] = al;
  }
  __syncthreads();

  // attention_output partial: out[b,e] += sum_r align[r] * mem[r,e]  (reuse LDS tile)
  int k0 = tid * 2;           // paired adjacent columns -> 4B LDS reads
  float a0 = 0.f, a1 = 0.f;
  #pragma unroll
  for (int r = 0; r < TILE_M; ++r) {
    float al = s_align[r];
    int sw = ((k0 >> 3) ^ (r & 7));
    bf16x2 m = *(const bf16x2*)&Afull[r*KP + sw*8 + (k0 & 7)];
    a0 += al * (float)m[0];
    a1 += al * (float)m[1];
  }
  atomicAdd(&out[b*Esz + k0],     a0);
  atomicAdd(&out[b*Esz + k0 + 1], a1);
}

// ---------------- softmax over T per batch row ----------------
__global__ __launch_bounds__(256) void softmax_kernel(
    const float* __restrict__ ws_align, float* __restrict__ out_w)
{
  int b = blockIdx.x, tid = threadIdx.x;
  const float* row = ws_align + (size_t)b*Tsz;
  float vals[8];
  float lmax = -3.4e38f;
  #pragma unroll
  for (int i = 0; i < 8; ++i) { vals[i] = row[tid + i*256]; lmax = fmaxf(lmax, vals[i]); }
  #pragma unroll
  for (int off = 1; off < 64; off <<= 1) lmax = fmaxf(lmax, __shfl_xor(lmax, off, 64));
  __shared__ float smax[4], ssum[4];
  if ((tid & 63) == 0) smax[tid >> 6] = lmax;
  __syncthreads();
  float bmax = fmaxf(fmaxf(smax[0], smax[1]), fmaxf(smax[2], smax[3]));
  float lsum = 0.f;
  #pragma unroll
  for (int i = 0; i < 8; ++i) { vals[i] = __expf(vals[i] - bmax); lsum += vals[i]; }
  #pragma unroll
  for (int off = 1; off < 64; off <<= 1) lsum += __shfl_xor(lsum, off, 64);
  if ((tid & 63) == 0) ssum[tid >> 6] = lsum;
  __syncthreads();
  float inv = 1.f / (ssum[0] + ssum[1] + ssum[2] + ssum[3]);
  #pragma unroll
  for (int i = 0; i < 8; ++i) out_w[(size_t)b*Tsz + tid + i*256] = vals[i] * inv;
}

extern "C" void kernel_launch(void* const* d_in, const int* in_sizes, int n_in,
                              void* d_out, int out_size, void* d_ws, size_t ws_size,
                              hipStream_t stream) {
  const float* ah   = (const float*)d_in[0];
  const float* mem  = (const float*)d_in[1];
  const float* awc  = (const float*)d_in[2];
  const int*   mask = (const int*)d_in[3];
  const float* Wq   = (const float*)d_in[4];
  const float* Wm   = (const float*)d_in[5];
  const float* cw   = (const float*)d_in[6];
  const float* Wl   = (const float*)d_in[7];
  const float* vw   = (const float*)d_in[8];
  const float* vb   = (const float*)d_in[9];
  float* out = (float*)d_out;

  // ws layout: Wext bf16 [128][576] (147456 B) | pq f32 [64][128] (32768 B) | align f32 [64][2048]
  bf16*  Wext = (bf16*)d_ws;
  float* pq   = (float*)((char*)d_ws + 147456);
  float* wsa  = (float*)((char*)d_ws + 180224);

  hipMemsetAsync(out, 0, Bsz*Esz*sizeof(float), stream);  // attention_output accumulators
  prep_kernel<<<dim3(224), 256, 0, stream>>>(Wm, cw, Wl, ah, Wq, Wext, pq);
  attn_main<<<dim3(Bsz*(Tsz/TILE_M)), 256, 0, stream>>>(mem, awc, mask, Wext, pq, vw, vb, out, wsa);
  softmax_kernel<<<dim3(Bsz), 256, 0, stream>>>(wsa, out + Bsz*Esz);
}